// Round 2
// baseline (237.003 us; speedup 1.0000x reference)
//
#include <hip/hip_runtime.h>

// Problem constants (from reference):
//   x: [B=32, C=1, F=257, T=4096] float32 log-magnitude spectrogram
//   SHIFT_BINS = 20.0 / (16000/512) = 0.64  -> f_low = f, f_high = f+1
//   out[b,f,t] = log10((1-a)*10^x[b,f,t] + a*10^x[b,f+1,t] + 1e-8), f < 256
//   out[b,256,t] = log10(1e-8)   (valid mask false at the top bin)
//
// Structure (round 2): each block produces ROWS=8 output rows for one b over
// half of T, reading ROWS+1=9 input rows. Row reuse (10^x[f] feeds out[f-1]
// and out[f]) is now in REGISTERS instead of across blocks on different XCDs.
// Read amplification at the L2/fabric level: 2.0x -> 1.125x. Transcendental
// work: pow10 computed once per element instead of twice.
#define B_DIM 32
#define F_DIM 257
#define T_DIM 4096
#define EPS_F 1e-8f

#define LOG2_10  3.32192809488736234787f
#define LOG10_2  0.30102999566398119521f

#define ROWS 8                       // output rows per block
#define FBLKS 32                     // 256 interp rows / ROWS
#define TCHUNKS 2
#define TCHUNK_F (T_DIM / TCHUNKS)   // 2048 floats per T-chunk
#define ROWV (T_DIM / 4)             // 1024 f32x4 per full row
#define NBLK (B_DIM * FBLKS * TCHUNKS)   // 2048 = 8 blocks/CU, fully resident
#define XCD_CHUNK (NBLK / 8)         // 256, bijective since NBLK % 8 == 0

typedef float f32x4 __attribute__((ext_vector_type(4)));

__device__ __forceinline__ float pow10_fast(float v) {
    // 10^v = 2^(v * log2(10)); v_exp_f32 is ~1 ulp — far under the absmax threshold
    return __builtin_amdgcn_exp2f(v * LOG2_10);
}
__device__ __forceinline__ float log10_fast(float v) {
    return __builtin_amdgcn_logf(v) * LOG10_2;  // v_log_f32 is log2
}
__device__ __forceinline__ f32x4 pow10_4(f32x4 v) {
    f32x4 r;
    r.x = pow10_fast(v.x); r.y = pow10_fast(v.y);
    r.z = pow10_fast(v.z); r.w = pow10_fast(v.w);
    return r;
}

__global__ __launch_bounds__(256) void freq_shift_kernel(
        const float* __restrict__ x, float* __restrict__ out) {
    // Bijective XCD-chunked swizzle: XCD k gets ids [k*256, (k+1)*256).
    // Consecutive ids walk fb fastest -> blocks sharing a boundary row are
    // temporal neighbors on the SAME XCD's L2.
    const int bid = blockIdx.x;
    const int id  = (bid & 7) * XCD_CHUNK + (bid >> 3);

    const int b   = id >> 6;          // 64 ids per b (2 tc x 32 fb)
    const int rem = id & 63;
    const int tc  = rem >> 5;
    const int fb  = rem & 31;
    const int f0  = fb * ROWS;
    const int tid = threadIdx.x;

    const long long base = ((long long)(b * F_DIM + f0)) * T_DIM + (long long)tc * TCHUNK_F;
    const f32x4* __restrict__ xin = (const f32x4*)(x + base);
    f32x4*       __restrict__ o   = (f32x4*)(out + base);

#pragma unroll
    for (int half = 0; half < 2; ++half) {
        const int c = tid + half * 256;      // f32x4 column within the T-chunk

        // Stage all 9 row-loads first: 9 global_load_dwordx4 in flight.
        f32x4 v[ROWS + 1];
#pragma unroll
        for (int r = 0; r <= ROWS; ++r) v[r] = xin[r * ROWV + c];

        // Streaming interp: pow10 of each row computed ONCE, reused for the
        // row below and the row above.
        f32x4 pprev = pow10_4(v[0]);
#pragma unroll
        for (int r = 0; r < ROWS; ++r) {
            // Reproduce reference fp32 alpha: target = fl(f + 0.64f); alpha = target - f
            const float ff    = (float)(f0 + r);
            const float alpha = (ff + 0.64f) - ff;
            const float beta  = 1.0f - alpha;

            const f32x4 pcur = pow10_4(v[r + 1]);
            f32x4 res;
            res.x = log10_fast(beta * pprev.x + alpha * pcur.x + EPS_F);
            res.y = log10_fast(beta * pprev.y + alpha * pcur.y + EPS_F);
            res.z = log10_fast(beta * pprev.z + alpha * pcur.z + EPS_F);
            res.w = log10_fast(beta * pprev.w + alpha * pcur.w + EPS_F);
            // out is write-once, never re-read: nontemporal store keeps L2
            // lines free for the boundary-row reuse.
            __builtin_nontemporal_store(res, o + r * ROWV + c);
            pprev = pcur;
        }
    }

    // Top bin f=256: log10(0 + 1e-8), constant. Handled by the fb==31 blocks
    // (64 blocks x 512 f32x4 x ... = full row coverage per (b,tc)).
    if (fb == FBLKS - 1) {
        const float cv = log10_fast(EPS_F);
        f32x4 vv; vv.x = cv; vv.y = cv; vv.z = cv; vv.w = cv;
        f32x4* orow = (f32x4*)(out + ((long long)(b * F_DIM + 256)) * T_DIM
                               + (long long)tc * TCHUNK_F);
        __builtin_nontemporal_store(vv, orow + tid);
        __builtin_nontemporal_store(vv, orow + tid + 256);
    }
}

extern "C" void kernel_launch(void* const* d_in, const int* in_sizes, int n_in,
                              void* d_out, int out_size, void* d_ws, size_t ws_size,
                              hipStream_t stream) {
    const float* x = (const float*)d_in[0];
    float* out = (float*)d_out;
    // 2048 blocks x 256 threads: 8 blocks/CU, whole grid co-resident.
    dim3 grid(NBLK);
    dim3 block(256);
    freq_shift_kernel<<<grid, block, 0, stream>>>(x, out);
}